// Round 1
// baseline (223.340 us; speedup 1.0000x reference)
//
#include <hip/hip_runtime.h>
#include <hip/hip_bf16.h>

constexpr int B_ = 4, N_ = 1024, DIM_ = 256, H_ = 8, DH_ = 32, PD_ = 16;

// ---------------- kernel 1: pos MLP -> s logits, layout [B*H][N] ----------------
__global__ __launch_bounds__(256) void k_pos_s(
    const float* __restrict__ pos, const float* __restrict__ Wp1,
    const float* __restrict__ bp1, const float* __restrict__ Wp2,
    const float* __restrict__ bp2, const float* __restrict__ Wh,
    float* __restrict__ Sl)
{
    __shared__ float sWp1[256], sbp1[16], sWp2[512], sbp2[32], sWh[256];
    int tid = threadIdx.x;
    sWp1[tid] = Wp1[tid];
    sWh[tid]  = Wh[tid];
    sWp2[tid] = Wp2[tid];
    sWp2[tid + 256] = Wp2[tid + 256];
    if (tid < 16) sbp1[tid] = bp1[tid];
    if (tid < 32) sbp2[tid] = bp2[tid];
    __syncthreads();

    int t = blockIdx.x * 256 + tid;       // 0..4095 = b*N + n
    int b = t >> 10, n = t & (N_ - 1);
    const float* prow = pos + (size_t)t * PD_;
    float pr[16];
#pragma unroll
    for (int r = 0; r < 16; ++r) pr[r] = prow[r];
    float h1[16];
#pragma unroll
    for (int c = 0; c < 16; ++c) {
        float a = sbp1[c];
#pragma unroll
        for (int r = 0; r < 16; ++r) a = fmaf(pr[r], sWp1[r * 16 + c], a);
        h1[c] = fmaxf(a, 0.0f);
    }
    float p[32];
#pragma unroll
    for (int d = 0; d < 32; ++d) {
        float a = sbp2[d];
#pragma unroll
        for (int c = 0; c < 16; ++c) a = fmaf(h1[c], sWp2[c * 32 + d], a);
        p[d] = a;
    }
#pragma unroll
    for (int h = 0; h < 8; ++h) {
        float a = 0.0f;
#pragma unroll
        for (int d = 0; d < 32; ++d) a = fmaf(p[d], sWh[d * 8 + h], a);
        // bh[h] omitted: constant across n, cancels in softmax over n
        Sl[(((b << 3) + h) << 10) + n] = a;
    }
}

// ---------------- kernel 2: w = softmax_n(-s) per (b,h) row ----------------
__global__ __launch_bounds__(256) void k_softmax_w(
    const float* __restrict__ Sl, float* __restrict__ Ww)
{
    int row = blockIdx.x;   // b*H + h
    const float4* s = (const float4*)(Sl + ((size_t)row << 10));
    float4* w = (float4*)(Ww + ((size_t)row << 10));
    int tid = threadIdx.x;
    float4 v = s[tid];
    float a0 = -v.x, a1 = -v.y, a2 = -v.z, a3 = -v.w;
    float mx = fmaxf(fmaxf(a0, a1), fmaxf(a2, a3));
#pragma unroll
    for (int off = 32; off >= 1; off >>= 1) mx = fmaxf(mx, __shfl_xor(mx, off));
    __shared__ float redm[4], reds[4];
    if ((tid & 63) == 0) redm[tid >> 6] = mx;
    __syncthreads();
    mx = fmaxf(fmaxf(redm[0], redm[1]), fmaxf(redm[2], redm[3]));
    float e0 = __expf(a0 - mx), e1 = __expf(a1 - mx);
    float e2 = __expf(a2 - mx), e3 = __expf(a3 - mx);
    float sum = e0 + e1 + e2 + e3;
#pragma unroll
    for (int off = 32; off >= 1; off >>= 1) sum += __shfl_xor(sum, off);
    if ((tid & 63) == 0) reds[tid >> 6] = sum;
    __syncthreads();
    float inv = 1.0f / (reds[0] + reds[1] + reds[2] + reds[3]);
    w[tid] = make_float4(e0 * inv, e1 * inv, e2 * inv, e3 * inv);
}

// ---------------- kernel 3: QKV GEMM, f32, 64x64 tiles, BK=32 ----------------
// Output layout: [B*H][N][DH] (head-major) for Q, K, V.
__global__ __launch_bounds__(256) void k_gemm_qkv(
    const float* __restrict__ X, const float* __restrict__ Wq,
    const float* __restrict__ Wk, const float* __restrict__ Wv,
    float* __restrict__ Q, float* __restrict__ Kc, float* __restrict__ Vc)
{
    __shared__ float As[32][65];  // [k][m]
    __shared__ float Bs[32][65];  // [k][n]
    int tid = threadIdx.x;
    int bx = blockIdx.x;          // 64 m-tiles
    int by = blockIdx.y;          // 12 = 3 mats x 4 col-tiles
    int mat = by >> 2;
    const float* W = (mat == 0) ? Wq : (mat == 1) ? Wk : Wv;
    int m0 = bx << 6, c0 = (by & 3) << 6;
    int tx = tid & 15, ty = tid >> 4;
    float acc[4][4] = {};
    for (int k0 = 0; k0 < 256; k0 += 32) {
#pragma unroll
        for (int l = 0; l < 2; ++l) {
            int lin = tid + l * 256;            // 64 rows x 8 float4
            int r = lin >> 3, c4 = (lin & 7) << 2;
            const float4 v = *(const float4*)(X + (size_t)(m0 + r) * 256 + k0 + c4);
            As[c4][r] = v.x; As[c4 + 1][r] = v.y; As[c4 + 2][r] = v.z; As[c4 + 3][r] = v.w;
        }
#pragma unroll
        for (int l = 0; l < 2; ++l) {
            int lin = tid + l * 256;            // 32 rows x 16 float4
            int k = lin >> 4, c4 = (lin & 15) << 2;
            const float4 v = *(const float4*)(W + (size_t)(k0 + k) * 256 + c0 + c4);
            Bs[k][c4] = v.x; Bs[k][c4 + 1] = v.y; Bs[k][c4 + 2] = v.z; Bs[k][c4 + 3] = v.w;
        }
        __syncthreads();
#pragma unroll
        for (int kk = 0; kk < 32; ++kk) {
            float a[4], bb[4];
#pragma unroll
            for (int i = 0; i < 4; ++i) a[i] = As[kk][ty * 4 + i];
#pragma unroll
            for (int j = 0; j < 4; ++j) bb[j] = Bs[kk][tx * 4 + j];
#pragma unroll
            for (int i = 0; i < 4; ++i)
#pragma unroll
                for (int j = 0; j < 4; ++j) acc[i][j] = fmaf(a[i], bb[j], acc[i][j]);
        }
        __syncthreads();
    }
    float* Dst = (mat == 0) ? Q : (mat == 1) ? Kc : Vc;
#pragma unroll
    for (int i = 0; i < 4; ++i) {
        int m = m0 + ty * 4 + i;
        int b = m >> 10, n = m & 1023;
#pragma unroll
        for (int j = 0; j < 4; ++j) {
            int c = c0 + tx * 4 + j;
            int h = c >> 5, d = c & 31;
            Dst[((size_t)((b << 3) + h) * N_ + n) * DH_ + d] = acc[i][j];
        }
    }
}

// ---------------- kernel 4: pv[b,h,:] = sum_n w[b,h,n] * V[b,h,n,:] ----------------
__global__ __launch_bounds__(256) void k_pv(
    const float* __restrict__ Vc, const float* __restrict__ Ww, float* __restrict__ Pv)
{
    int row = blockIdx.x;   // b*H + h
    const float* V = Vc + ((size_t)row << 10) * DH_;
    const float* w = Ww + ((size_t)row << 10);
    int tid = threadIdx.x;
    int d = tid & 31, g = tid >> 5;   // 8 n-groups x 32 dims
    float acc = 0.0f;
    for (int n = g; n < N_; n += 8) acc = fmaf(w[n], V[n * DH_ + d], acc);
    __shared__ float red[8][32];
    red[g][d] = acc;
    __syncthreads();
    if (g == 0) {
        float s = 0.0f;
#pragma unroll
        for (int i = 0; i < 8; ++i) s += red[i][d];
        Pv[row * DH_ + d] = s;
    }
}

// ---------------- kernel 5: flash attention f32 + gated combine ----------------
// grid: (qt=16, bh=32); 64-row Q tile; online softmax; epilogue fuses
// (1-g)*softmax(QK^T/sqrt(dh))@V + g*pv into out_head [B][N][DIM].
__global__ __launch_bounds__(256) void k_attn(
    const float* __restrict__ Q, const float* __restrict__ Kc,
    const float* __restrict__ Vc, const float* __restrict__ Pv,
    const float* __restrict__ gate, float* __restrict__ OH)
{
    __shared__ float Qs[64][33], Ks[64][33], Vs[64][33], Ss[64][65];
    int tid = threadIdx.x;
    int qt = blockIdx.x, bhid = blockIdx.y;
    int b = bhid >> 3, h = bhid & 7;
    const float* Qp = Q + ((size_t)bhid * N_ + qt * 64) * DH_;
    const float* Kp = Kc + (size_t)bhid * N_ * DH_;
    const float* Vp = Vc + (size_t)bhid * N_ * DH_;

#pragma unroll
    for (int l = 0; l < 2; ++l) {
        int lin = tid + l * 256;
        int r = lin >> 3, c4 = (lin & 7) << 2;
        const float4 v = *(const float4*)(Qp + r * DH_ + c4);
        Qs[r][c4] = v.x; Qs[r][c4 + 1] = v.y; Qs[r][c4 + 2] = v.z; Qs[r][c4 + 3] = v.w;
    }

    float O[8] = {0, 0, 0, 0, 0, 0, 0, 0};
    float m_r = -1e30f, l_r = 0.0f;
    int rr = tid >> 2;            // row 0..63
    int qq = tid & 3;             // 4 lanes per row
    int d0 = qq << 3;             // 8 output dims per lane
    int tx = tid & 15, ty = tid >> 4;
    const float sscale = 0.17677669529663687f;  // 1/sqrt(32)

    for (int kt = 0; kt < 16; ++kt) {
        __syncthreads();          // protect Ks/Vs/Ss from previous iteration
        const float* Kt = Kp + kt * 64 * DH_;
        const float* Vt = Vp + kt * 64 * DH_;
#pragma unroll
        for (int l = 0; l < 2; ++l) {
            int lin = tid + l * 256;
            int r = lin >> 3, c4 = (lin & 7) << 2;
            float4 v = *(const float4*)(Kt + r * DH_ + c4);
            Ks[r][c4] = v.x; Ks[r][c4 + 1] = v.y; Ks[r][c4 + 2] = v.z; Ks[r][c4 + 3] = v.w;
            v = *(const float4*)(Vt + r * DH_ + c4);
            Vs[r][c4] = v.x; Vs[r][c4 + 1] = v.y; Vs[r][c4 + 2] = v.z; Vs[r][c4 + 3] = v.w;
        }
        __syncthreads();
        // 64x64 scores, 4x4 per thread
        float sc[4][4] = {};
#pragma unroll
        for (int dd = 0; dd < 32; ++dd) {
            float a[4], bb[4];
#pragma unroll
            for (int i = 0; i < 4; ++i) a[i] = Qs[ty * 4 + i][dd];
#pragma unroll
            for (int j = 0; j < 4; ++j) bb[j] = Ks[tx * 4 + j][dd];
#pragma unroll
            for (int i = 0; i < 4; ++i)
#pragma unroll
                for (int j = 0; j < 4; ++j) sc[i][j] = fmaf(a[i], bb[j], sc[i][j]);
        }
#pragma unroll
        for (int i = 0; i < 4; ++i)
#pragma unroll
            for (int j = 0; j < 4; ++j)
                Ss[ty * 4 + i][tx * 4 + j] = sc[i][j] * sscale;
        __syncthreads();
        // online softmax: row rr owned by 4 contiguous lanes (shfl-group)
        float tmax = -1e30f;
#pragma unroll
        for (int t2 = 0; t2 < 16; ++t2) tmax = fmaxf(tmax, Ss[rr][(qq << 4) + t2]);
        tmax = fmaxf(tmax, __shfl_xor(tmax, 1));
        tmax = fmaxf(tmax, __shfl_xor(tmax, 2));
        float newm = fmaxf(m_r, tmax);
        float corr = __expf(m_r - newm);
        float psum = 0.0f;
#pragma unroll
        for (int t2 = 0; t2 < 16; ++t2) {
            float pe = __expf(Ss[rr][(qq << 4) + t2] - newm);
            Ss[rr][(qq << 4) + t2] = pe;   // same-wave write, read below by same group
            psum += pe;
        }
        psum += __shfl_xor(psum, 1);
        psum += __shfl_xor(psum, 2);
        l_r = l_r * corr + psum;
        m_r = newm;
#pragma unroll
        for (int t2 = 0; t2 < 8; ++t2) O[t2] *= corr;
        // P @ V for this tile
#pragma unroll 4
        for (int j = 0; j < 64; ++j) {
            float pj = Ss[rr][j];
#pragma unroll
            for (int t2 = 0; t2 < 8; ++t2) O[t2] = fmaf(pj, Vs[j][d0 + t2], O[t2]);
        }
    }
    // epilogue: normalize, gate-combine with pv, write out_head
    float gh = 1.0f / (1.0f + __expf(-gate[h]));
    float inv_l = 1.0f / l_r;
    int n = qt * 64 + rr;
    float* dst = OH + (size_t)(b * N_ + n) * DIM_ + h * DH_ + d0;
    const float* pvp = Pv + bhid * DH_ + d0;
#pragma unroll
    for (int t2 = 0; t2 < 8; ++t2)
        dst[t2] = (1.0f - gh) * (O[t2] * inv_l) + gh * pvp[t2];
}

// ---------------- kernel 6: out = OH @ Wo + bo ----------------
__global__ __launch_bounds__(256) void k_gemm_out(
    const float* __restrict__ A, const float* __restrict__ Wo,
    const float* __restrict__ bo, float* __restrict__ out)
{
    __shared__ float As[32][65];
    __shared__ float Bs[32][65];
    int tid = threadIdx.x;
    int bx = blockIdx.x, by = blockIdx.y;   // 64 x 4
    int m0 = bx << 6, c0 = by << 6;
    int tx = tid & 15, ty = tid >> 4;
    float acc[4][4] = {};
    for (int k0 = 0; k0 < 256; k0 += 32) {
#pragma unroll
        for (int l = 0; l < 2; ++l) {
            int lin = tid + l * 256;
            int r = lin >> 3, c4 = (lin & 7) << 2;
            const float4 v = *(const float4*)(A + (size_t)(m0 + r) * 256 + k0 + c4);
            As[c4][r] = v.x; As[c4 + 1][r] = v.y; As[c4 + 2][r] = v.z; As[c4 + 3][r] = v.w;
        }
#pragma unroll
        for (int l = 0; l < 2; ++l) {
            int lin = tid + l * 256;
            int k = lin >> 4, c4 = (lin & 15) << 2;
            const float4 v = *(const float4*)(Wo + (size_t)(k0 + k) * 256 + c0 + c4);
            Bs[k][c4] = v.x; Bs[k][c4 + 1] = v.y; Bs[k][c4 + 2] = v.z; Bs[k][c4 + 3] = v.w;
        }
        __syncthreads();
#pragma unroll
        for (int kk = 0; kk < 32; ++kk) {
            float a[4], bb[4];
#pragma unroll
            for (int i = 0; i < 4; ++i) a[i] = As[kk][ty * 4 + i];
#pragma unroll
            for (int j = 0; j < 4; ++j) bb[j] = Bs[kk][tx * 4 + j];
#pragma unroll
            for (int i = 0; i < 4; ++i)
#pragma unroll
                for (int j = 0; j < 4; ++j) acc[i][j] = fmaf(a[i], bb[j], acc[i][j]);
        }
        __syncthreads();
    }
#pragma unroll
    for (int i = 0; i < 4; ++i) {
        int m = m0 + ty * 4 + i;
#pragma unroll
        for (int j = 0; j < 4; ++j) {
            int c = c0 + tx * 4 + j;
            out[(size_t)m * 256 + c] = acc[i][j] + bo[c];
        }
    }
}

extern "C" void kernel_launch(void* const* d_in, const int* in_sizes, int n_in,
                              void* d_out, int out_size, void* d_ws, size_t ws_size,
                              hipStream_t stream) {
    const float* x    = (const float*)d_in[0];
    // d_in[1] = deep_semantics: unused by the reference
    const float* pos  = (const float*)d_in[2];
    const float* Wq   = (const float*)d_in[3];
    const float* Wk   = (const float*)d_in[4];
    const float* Wv   = (const float*)d_in[5];
    const float* Wo   = (const float*)d_in[6];
    const float* bo   = (const float*)d_in[7];
    const float* Wp1  = (const float*)d_in[8];
    const float* bp1  = (const float*)d_in[9];
    const float* Wp2  = (const float*)d_in[10];
    const float* bp2  = (const float*)d_in[11];
    const float* Wh   = (const float*)d_in[12];
    // d_in[13] = bh: cancels in softmax over keys, unused
    const float* gate = (const float*)d_in[14];
    float* out = (float*)d_out;

    float* ws = (float*)d_ws;
    float* Q   = ws;               // [B*H][N][DH] 1048576
    float* Kc  = Q + 1048576;      // 1048576
    float* Vc  = Kc + 1048576;     // 1048576
    float* Sl  = Vc + 1048576;     // [B*H][N] 32768
    float* Ww  = Sl + 32768;       // 32768
    float* Pv  = Ww + 32768;       // [B*H][DH] 1024
    float* OH  = Pv + 1024;        // [B][N][DIM] 1048576

    k_pos_s   <<<dim3(16),     dim3(256), 0, stream>>>(pos, Wp1, bp1, Wp2, bp2, Wh, Sl);
    k_softmax_w<<<dim3(32),    dim3(256), 0, stream>>>(Sl, Ww);
    k_gemm_qkv<<<dim3(64, 12), dim3(256), 0, stream>>>(x, Wq, Wk, Wv, Q, Kc, Vc);
    k_pv      <<<dim3(32),     dim3(256), 0, stream>>>(Vc, Ww, Pv);
    k_attn    <<<dim3(16, 32), dim3(256), 0, stream>>>(Q, Kc, Vc, Pv, gate, OH);
    k_gemm_out<<<dim3(64, 4),  dim3(256), 0, stream>>>(OH, Wo, bo, out);
}

// Round 2
// 66.813 us; speedup vs baseline: 3.3428x; 3.3428x over previous
//
#include <hip/hip_runtime.h>
#include <hip/hip_bf16.h>

// ============================================================================
// Algebraic structure (exact, verified round 1 at absmax 4.9e-4):
//   pos_logits[b,h,i,j] = s[b,h,i] - s[b,h,j] + bh[h]  (rank-1 in i)
//   => pos_attn rows are identical: w[b,h,j] = softmax_j(-s[b,h,j])
//   => out_head = (1-g)*softmax(QK^T/sqrt(dh))@V + g*(w@V);  renorm is a no-op.
// This round: bf16 MFMA everywhere (32x32x16), f32 accumulation.
//   C/D layout: col = lane&31, row = (reg&3)+8*(reg>>2)+4*(lane>>5)   [verified]
//   A-frag: A[lane&31][(lane>>5)*8+jj]; B-frag: B[(lane>>5)*8+jj][lane&31]
// ============================================================================

constexpr int B_ = 4, N_ = 1024, DIM_ = 256, H_ = 8, DH_ = 32, PD_ = 16;

typedef short  s8v  __attribute__((ext_vector_type(8)));
typedef float  f16v __attribute__((ext_vector_type(16)));
typedef unsigned u4v __attribute__((ext_vector_type(4)));

__device__ inline unsigned pkbf(float lo, float hi) {
  unsigned r;
  asm("v_cvt_pk_bf16_f32 %0, %1, %2" : "=v"(r) : "v"(lo), "v"(hi));
  return r;
}
__device__ inline short bf16r(float f) {   // RNE f32->bf16
  unsigned u = __float_as_uint(f);
  u += 0x7fff + ((u >> 16) & 1);
  return (short)(u >> 16);
}
__device__ inline float bflo(unsigned w) { return __uint_as_float(w << 16); }
__device__ inline float bfhi(unsigned w) { return __uint_as_float(w & 0xffff0000u); }

// ---------------- prep: W^T -> bf16 (Wq pre-scaled by log2e/sqrt(32)) -------
__global__ __launch_bounds__(256) void k_prep_w(
    const float* __restrict__ Wq, const float* __restrict__ Wk,
    const float* __restrict__ Wv, const float* __restrict__ Wo,
    short* __restrict__ Wt, short* __restrict__ Wot)
{
  __shared__ float tile[64][65];
  int bid = blockIdx.x;
  int mat = bid >> 4, t = bid & 15;
  int k0 = (t >> 2) * 64, c0 = (t & 3) * 64;
  const float* W = mat == 0 ? Wq : mat == 1 ? Wk : mat == 2 ? Wv : Wo;
  float scale = (mat == 0) ? 0.2550348662f : 1.0f;   // log2(e)/sqrt(32)
  int tid = threadIdx.x;
#pragma unroll
  for (int i = 0; i < 16; ++i) {
    int e = tid + i * 256;
    int kr = e >> 6, cc = e & 63;
    tile[kr][cc] = W[(size_t)(k0 + kr) * 256 + c0 + cc];
  }
  __syncthreads();
  short* dst = (mat == 3) ? Wot : (Wt + mat * 65536);
#pragma unroll
  for (int i = 0; i < 16; ++i) {
    int e = tid + i * 256;
    int cr = e >> 6, kk = e & 63;
    dst[(size_t)(c0 + cr) * 256 + k0 + kk] = bf16r(tile[kk][cr] * scale);
  }
}

// ---------------- x -> bf16 ----------------
__global__ __launch_bounds__(256) void k_cvt_x(
    const float* __restrict__ x, short* __restrict__ xb)
{
  int idx = blockIdx.x * 256 + threadIdx.x;   // 8 elements each
  const float4* p = (const float4*)(x + (size_t)idx * 8);
  float4 f0 = p[0], f1 = p[1];
  u4v o = { pkbf(f0.x, f0.y), pkbf(f0.z, f0.w), pkbf(f1.x, f1.y), pkbf(f1.z, f1.w) };
  *(u4v*)(xb + (size_t)idx * 8) = o;
}

// ---------------- pos MLP -> s logits [B*H][N] (f32, exact) ----------------
__global__ __launch_bounds__(256) void k_pos_s(
    const float* __restrict__ pos, const float* __restrict__ Wp1,
    const float* __restrict__ bp1, const float* __restrict__ Wp2,
    const float* __restrict__ bp2, const float* __restrict__ Wh,
    float* __restrict__ Sl)
{
  __shared__ float sWp1[256], sbp1[16], sWp2[512], sbp2[32], sWh[256];
  int tid = threadIdx.x;
  sWp1[tid] = Wp1[tid];
  sWh[tid]  = Wh[tid];
  sWp2[tid] = Wp2[tid];
  sWp2[tid + 256] = Wp2[tid + 256];
  if (tid < 16) sbp1[tid] = bp1[tid];
  if (tid < 32) sbp2[tid] = bp2[tid];
  __syncthreads();

  int t = blockIdx.x * 256 + tid;
  int b = t >> 10, n = t & (N_ - 1);
  const float* prow = pos + (size_t)t * PD_;
  float pr[16];
#pragma unroll
  for (int r = 0; r < 16; ++r) pr[r] = prow[r];
  float h1[16];
#pragma unroll
  for (int c = 0; c < 16; ++c) {
    float a = sbp1[c];
#pragma unroll
    for (int r = 0; r < 16; ++r) a = fmaf(pr[r], sWp1[r * 16 + c], a);
    h1[c] = fmaxf(a, 0.0f);
  }
  float p[32];
#pragma unroll
  for (int d = 0; d < 32; ++d) {
    float a = sbp2[d];
#pragma unroll
    for (int c = 0; c < 16; ++c) a = fmaf(h1[c], sWp2[c * 32 + d], a);
    p[d] = a;
  }
#pragma unroll
  for (int h = 0; h < 8; ++h) {
    float a = 0.0f;
#pragma unroll
    for (int d = 0; d < 32; ++d) a = fmaf(p[d], sWh[d * 8 + h], a);
    Sl[(((b << 3) + h) << 10) + n] = a;   // bh[h] cancels in softmax
  }
}

// ---------------- w = softmax_n(-s) ----------------
__global__ __launch_bounds__(256) void k_softmax_w(
    const float* __restrict__ Sl, float* __restrict__ Ww)
{
  int row = blockIdx.x;
  const float4* s = (const float4*)(Sl + ((size_t)row << 10));
  float4* w = (float4*)(Ww + ((size_t)row << 10));
  int tid = threadIdx.x;
  float4 v = s[tid];
  float a0 = -v.x, a1 = -v.y, a2 = -v.z, a3 = -v.w;
  float mx = fmaxf(fmaxf(a0, a1), fmaxf(a2, a3));
#pragma unroll
  for (int off = 32; off >= 1; off >>= 1) mx = fmaxf(mx, __shfl_xor(mx, off));
  __shared__ float redm[4], reds[4];
  if ((tid & 63) == 0) redm[tid >> 6] = mx;
  __syncthreads();
  mx = fmaxf(fmaxf(redm[0], redm[1]), fmaxf(redm[2], redm[3]));
  float e0 = __expf(a0 - mx), e1 = __expf(a1 - mx);
  float e2 = __expf(a2 - mx), e3 = __expf(a3 - mx);
  float sum = e0 + e1 + e2 + e3;
#pragma unroll
  for (int off = 32; off >= 1; off >>= 1) sum += __shfl_xor(sum, off);
  if ((tid & 63) == 0) reds[tid >> 6] = sum;
  __syncthreads();
  float inv = 1.0f / (reds[0] + reds[1] + reds[2] + reds[3]);
  w[tid] = make_float4(e0 * inv, e1 * inv, e2 * inv, e3 * inv);
}

// ---------------- QKV GEMM: bf16 MFMA, 32x32 tile per wave ------------------
// Q/K head-major [bh][n][32]; V written transposed: Vt[bh][d][n].
__global__ __launch_bounds__(256) void k_gemm_qkv(
    const short* __restrict__ xb, const short* __restrict__ Wt,
    short* __restrict__ Qb, short* __restrict__ Kb, short* __restrict__ Vtb)
{
  int tid = threadIdx.x;
  int w = tid >> 6, l = tid & 63, H = l >> 5, li = l & 31;
  int bid = blockIdx.x;
  int cb = bid % 12, mb = bid / 12;
  int m0 = mb * 64 + (w & 1) * 32;
  int c0 = cb * 64 + (w >> 1) * 32;       // 0..767 = 3 mats x 256
  const short* Ap = xb + (size_t)(m0 + li) * 256 + 8 * H;
  const short* Bp = Wt + (size_t)(c0 + li) * 256 + 8 * H;
  f16v acc = {};
#pragma unroll
  for (int kc = 0; kc < 16; ++kc) {
    s8v af = *(const s8v*)(Ap + 16 * kc);
    s8v bf = *(const s8v*)(Bp + 16 * kc);
    acc = __builtin_amdgcn_mfma_f32_32x32x16_bf16(af, bf, acc, 0, 0, 0);
  }
  int mat = c0 >> 8, mc = c0 & 255;
  int h = mc >> 5;
  int b = m0 >> 10, nb = m0 & 1023;
  int bh = b * 8 + h;
  if (mat < 2) {
    short* Dst = (mat == 0) ? Qb : Kb;
#pragma unroll
    for (int r = 0; r < 16; ++r) {
      int crow = (r & 3) + 8 * (r >> 2) + 4 * H;
      Dst[((size_t)(bh * 1024 + nb + crow)) * 32 + li] = bf16r(acc[r]);
    }
  } else {
#pragma unroll
    for (int q2 = 0; q2 < 4; ++q2) {
      uint2 val = make_uint2(pkbf(acc[q2 * 4 + 0], acc[q2 * 4 + 1]),
                             pkbf(acc[q2 * 4 + 2], acc[q2 * 4 + 3]));
      *(uint2*)(Vtb + ((size_t)(bh * 32 + li)) * 1024 + nb + 8 * q2 + 4 * H) = val;
    }
  }
}

// ---------------- pv[bh][d] = sum_n w[bh][n] * V[n][d]  (reads Vt bf16) -----
__global__ __launch_bounds__(256) void k_pv(
    const short* __restrict__ Vtb, const float* __restrict__ Ww,
    float* __restrict__ pv)
{
  int bh = blockIdx.x, tid = threadIdx.x;
  int d = tid >> 3, sub = tid & 7;
  const short* Vp = Vtb + ((size_t)(bh * 32 + d)) * 1024 + sub * 128;
  const float* wp = Ww + bh * 1024 + sub * 128;
  float s = 0.f;
  for (int n = 0; n < 128; n += 8) {
    s8v v = *(const s8v*)(Vp + n);
#pragma unroll
    for (int j = 0; j < 8; ++j)
      s = fmaf(wp[n + j], __uint_as_float(((unsigned)(unsigned short)v[j]) << 16), s);
  }
  __shared__ float red[32][9];
  red[d][sub] = s;
  __syncthreads();
  if (tid < 32) {
    float a = 0.f;
#pragma unroll
    for (int j = 0; j < 8; ++j) a += red[tid][j];
    pv[bh * 32 + tid] = a;
  }
}

// ---------------- flash attention: swapped-operand MFMA, exp2 domain --------
// grid 1024 = (qb,bh) XCD-swizzled; 4 waves split the 1024 keys; LDS combine.
__global__ __launch_bounds__(256) void k_attn(
    const short* __restrict__ Qb, const short* __restrict__ Kb,
    const short* __restrict__ Vtb, const float* __restrict__ pv,
    const float* __restrict__ gate, float* __restrict__ OH)
{
  __shared__ float sml[2][4][32];
  __shared__ float sO[4][32][33];
  int tid = threadIdx.x;
  int w = tid >> 6, l = tid & 63;
  int H = l >> 5, li = l & 31;
  int bid = blockIdx.x;
  int bh = (bid & 7) * 4 + (bid >> 8);    // same-bh blocks -> same XCD L2
  int qb = (bid >> 3) & 31;
  int n0 = qb * 32;

  // Q fragments (Wq pre-scaled by log2e/sqrt(32) => S is already in exp2 units)
  const short* Qp = Qb + ((size_t)(bh * 1024 + n0 + li)) * 32 + 8 * H;
  s8v qf0 = *(const s8v*)(Qp);
  s8v qf1 = *(const s8v*)(Qp + 16);

  const short* Kbase = Kb + ((size_t)(bh * 1024)) * 32 + 8 * H;
  const short* Vbase = Vtb + ((size_t)(bh * 32 + li)) * 1024 + 8 * H;

  f16v acc = {};                 // O^T[d][i]: col i = li, row d = crow(reg,H)
  float m = -1e30f, lsum = 0.0f;

  for (int ch = 0; ch < 8; ++ch) {
    int jb = w * 256 + ch * 32;
    const short* Kp = Kbase + (size_t)(jb + li) * 32;
    s8v kf0 = *(const s8v*)(Kp);
    s8v kf1 = *(const s8v*)(Kp + 16);
    const short* Vp = Vbase + jb;
    s8v vf0 = *(const s8v*)(Vp);        // j_local 0..15
    s8v vf1 = *(const s8v*)(Vp + 16);   // j_local 16..31

    // S^T[j][i] = K . Q^T : lane holds i = li, j = (reg&3)+8*(reg>>2)+4H
    f16v S = {};
    S = __builtin_amdgcn_mfma_f32_32x32x16_bf16(kf0, qf0, S, 0, 0, 0);
    S = __builtin_amdgcn_mfma_f32_32x32x16_bf16(kf1, qf1, S, 0, 0, 0);

    float cmax = S[0];
#pragma unroll
    for (int r = 1; r < 16; ++r) cmax = fmaxf(cmax, S[r]);
    cmax = fmaxf(cmax, __shfl_xor(cmax, 32));
    bool grow = !__all(cmax <= m + 11.0f);       // defer-max (T13), exp2 units
    float mn = grow ? fmaxf(m, cmax) : m;
    float p[16], sum = 0.f;
#pragma unroll
    for (int r = 0; r < 16; ++r) {
      p[r] = __builtin_amdgcn_exp2f(S[r] - mn);
      sum += p[r];
    }
    sum += __shfl_xor(sum, 32);
    if (grow) {
      float corr = __builtin_amdgcn_exp2f(m - mn);
      lsum *= corr;
#pragma unroll
      for (int r = 0; r < 16; ++r) acc[r] *= corr;
      m = mn;
    }
    lsum += sum;

    // repack p -> PV B-operand (P[i][j] with j = 16kc+8H+jj), in-register.
    // word0 = (H? sx(b):a), word2 = (H? b: sx(a)) per (a,b)=(regs r..r+1, r+4..r+5)
    unsigned a0 = pkbf(p[0], p[1]),  a1 = pkbf(p[2], p[3]);
    unsigned b0 = pkbf(p[4], p[5]),  b1 = pkbf(p[6], p[7]);
    unsigned c0 = pkbf(p[8], p[9]),  c1 = pkbf(p[10], p[11]);
    unsigned d0 = pkbf(p[12], p[13]), d1 = pkbf(p[14], p[15]);
    unsigned sa0 = __shfl_xor(a0, 32), sa1 = __shfl_xor(a1, 32);
    unsigned sb0 = __shfl_xor(b0, 32), sb1 = __shfl_xor(b1, 32);
    unsigned sc0 = __shfl_xor(c0, 32), sc1 = __shfl_xor(c1, 32);
    unsigned sd0 = __shfl_xor(d0, 32), sd1 = __shfl_xor(d1, 32);
    u4v t0 = { H ? sb0 : a0, H ? sb1 : a1, H ? b0 : sa0, H ? b1 : sa1 };
    u4v t1 = { H ? sd0 : c0, H ? sd1 : c1, H ? d0 : sc0, H ? d1 : sc1 };
    s8v pf0 = __builtin_bit_cast(s8v, t0);
    s8v pf1 = __builtin_bit_cast(s8v, t1);

    // O^T += Vt . P^T
    acc = __builtin_amdgcn_mfma_f32_32x32x16_bf16(vf0, pf0, acc, 0, 0, 0);
    acc = __builtin_amdgcn_mfma_f32_32x32x16_bf16(vf1, pf1, acc, 0, 0, 0);
  }

  if (H == 0) { sml[0][w][li] = m; sml[1][w][li] = lsum; }
#pragma unroll
  for (int r = 0; r < 16; ++r) {
    int d = (r & 3) + 8 * (r >> 2) + 4 * H;
    sO[w][d][li] = acc[r];
  }
  __syncthreads();

  // combine 4 wave-partials, gate with pv, write OH (f32)
  int i = tid >> 3, dq = (tid & 7) * 4;
  float m0w = sml[0][0][i], m1w = sml[0][1][i], m2w = sml[0][2][i], m3w = sml[0][3][i];
  float M = fmaxf(fmaxf(m0w, m1w), fmaxf(m2w, m3w));
  float e0 = __builtin_amdgcn_exp2f(m0w - M), e1 = __builtin_amdgcn_exp2f(m1w - M);
  float e2 = __builtin_amdgcn_exp2f(m2w - M), e3 = __builtin_amdgcn_exp2f(m3w - M);
  float L = sml[1][0][i] * e0 + sml[1][1][i] * e1 + sml[1][2][i] * e2 + sml[1][3][i] * e3;
  int b = bh >> 3, h = bh & 7;
  float gh = 1.0f / (1.0f + __expf(-gate[h]));
  float invL = (1.0f - gh) / L;
  const float4 pvv = *(const float4*)(pv + bh * 32 + dq);
  float4 o;
  o.x = (sO[0][dq + 0][i] * e0 + sO[1][dq + 0][i] * e1 + sO[2][dq + 0][i] * e2 + sO[3][dq + 0][i] * e3) * invL + gh * pvv.x;
  o.y = (sO[0][dq + 1][i] * e0 + sO[1][dq + 1][i] * e1 + sO[2][dq + 1][i] * e2 + sO[3][dq + 1][i] * e3) * invL + gh * pvv.y;
  o.z = (sO[0][dq + 2][i] * e0 + sO[1][dq + 2][i] * e1 + sO[2][dq + 2][i] * e2 + sO[3][dq + 2][i] * e3) * invL + gh * pvv.z;
  o.w = (sO[0][dq + 3][i] * e0 + sO[1][dq + 3][i] * e1 + sO[2][dq + 3][i] * e2 + sO[3][dq + 3][i] * e3) * invL + gh * pvv.w;
  *(float4*)(OH + ((size_t)(b * 1024 + n0 + i)) * 256 + h * 32 + dq) = o;
}

// ---------------- out = OH @ Wo + bo  (split-bf16 A: exact to ~1e-4) --------
__global__ __launch_bounds__(256) void k_gemm_out(
    const float* __restrict__ OH, const short* __restrict__ Wot,
    const float* __restrict__ bo, float* __restrict__ out)
{
  int tid = threadIdx.x;
  int w = tid >> 6, l = tid & 63, H = l >> 5, li = l & 31;
  int bid = blockIdx.x;
  int m0 = (bid >> 2) * 64 + (w & 1) * 32;
  int c0 = (bid & 3) * 64 + (w >> 1) * 32;
  const float* Ap = OH + (size_t)(m0 + li) * 256 + 8 * H;
  const short* Bp = Wot + (size_t)(c0 + li) * 256 + 8 * H;
  f16v acc = {};
#pragma unroll
  for (int kc = 0; kc < 16; ++kc) {
    float4 f0 = *(const float4*)(Ap + 16 * kc);
    float4 f1 = *(const float4*)(Ap + 16 * kc + 4);
    unsigned h0 = pkbf(f0.x, f0.y), h1 = pkbf(f0.z, f0.w);
    unsigned h2 = pkbf(f1.x, f1.y), h3 = pkbf(f1.z, f1.w);
    float r0 = f0.x - bflo(h0), r1 = f0.y - bfhi(h0);
    float r2 = f0.z - bflo(h1), r3 = f0.w - bfhi(h1);
    float r4 = f1.x - bflo(h2), r5 = f1.y - bfhi(h2);
    float r6 = f1.z - bflo(h3), r7 = f1.w - bfhi(h3);
    u4v th = { h0, h1, h2, h3 };
    u4v tl = { pkbf(r0, r1), pkbf(r2, r3), pkbf(r4, r5), pkbf(r6, r7) };
    s8v bf = *(const s8v*)(Bp + 16 * kc);
    acc = __builtin_amdgcn_mfma_f32_32x32x16_bf16(__builtin_bit_cast(s8v, th), bf, acc, 0, 0, 0);
    acc = __builtin_amdgcn_mfma_f32_32x32x16_bf16(__builtin_bit_cast(s8v, tl), bf, acc, 0, 0, 0);
  }
  float bias = bo[c0 + li];
#pragma unroll
  for (int r = 0; r < 16; ++r) {
    int crow = (r & 3) + 8 * (r >> 2) + 4 * H;
    out[(size_t)(m0 + crow) * 256 + c0 + li] = acc[r] + bias;
  }
}

// ============================================================================
extern "C" void kernel_launch(void* const* d_in, const int* in_sizes, int n_in,
                              void* d_out, int out_size, void* d_ws, size_t ws_size,
                              hipStream_t stream) {
  const float* x    = (const float*)d_in[0];
  // d_in[1] = deep_semantics: unused by the reference
  const float* pos  = (const float*)d_in[2];
  const float* Wq   = (const float*)d_in[3];
  const float* Wk   = (const float*)d_in[4];
  const float* Wv   = (const float*)d_in[5];
  const float* Wo   = (const float*)d_in[6];
  const float* bo   = (const float*)d_in[7];
  const float* Wp1  = (const float*)d_in[8];
  const float* bp1  = (const float*)d_in[9];
  const float* Wp2  = (const float*)d_in[10];
  const float* bp2  = (const float*)d_in[11];
  const float* Wh   = (const float*)d_in[12];
  // d_in[13] = bh: cancels in softmax over keys
  const float* gate = (const float*)d_in[14];
  float* out = (float*)d_out;

  char* base = (char*)d_ws;
  short* Qb  = (short*)(base);                              // 2MB [32bh][1024][32]
  short* Kb  = (short*)(base + (2u << 20));                 // 2MB
  short* Vtb = (short*)(base + (4u << 20));                 // 2MB [32bh][32][1024]
  short* xb  = (short*)(base + (6u << 20));                 // 2MB [4096][256]
  short* Wt  = (short*)(base + (8u << 20));                 // 384KB [768][256]
  short* Wot = (short*)(base + (8u << 20) + (384u << 10));  // 128KB [256][256]
  float* Sl  = (float*)(base + (8u << 20) + (512u << 10));  // 128KB
  float* Ww  = (float*)(base + (8u << 20) + (640u << 10));  // 128KB
  float* pv  = (float*)(base + (8u << 20) + (768u << 10));  // 4KB
  float* OH  = (float*)(base + (9u << 20));                 // 4MB [4096][256]

  k_prep_w  <<<64,   256, 0, stream>>>(Wq, Wk, Wv, Wo, Wt, Wot);
  k_cvt_x   <<<512,  256, 0, stream>>>(x, xb);
  k_pos_s   <<<16,   256, 0, stream>>>(pos, Wp1, bp1, Wp2, bp2, Wh, Sl);
  k_softmax_w<<<32,  256, 0, stream>>>(Sl, Ww);
  k_gemm_qkv<<<768,  256, 0, stream>>>(xb, Wt, Qb, Kb, Vtb);
  k_pv      <<<32,   256, 0, stream>>>(Vtb, Ww, pv);
  k_attn    <<<1024, 256, 0, stream>>>(Qb, Kb, Vtb, pv, gate, OH);
  k_gemm_out<<<256,  256, 0, stream>>>(OH, Wot, bo, out);
}